// Round 4
// baseline (12672.121 us; speedup 1.0000x reference)
//
#include <hip/hip_runtime.h>

#define B_  128
#define S_  256
#define E_  300
#define EP_ 320
#define H_  512
#define G_  2048   // 4*H
#define D1_ 1024   // 2*H

typedef _Float16 f16;
typedef __attribute__((ext_vector_type(8))) _Float16 f16x8;
typedef __attribute__((ext_vector_type(4))) float    f32x4;

__device__ __forceinline__ float sigf(float x){ return 1.f/(1.f + __expf(-x)); }
__device__ __forceinline__ float tanhf_(float x){
  float e = __expf(-2.f*fabsf(x));
  float t = (1.f - e)/(1.f + e);
  return x < 0.f ? -t : t;
}

// ---- per-step slot barrier (no reset -> no reuse race). Device scope. ----
__device__ __forceinline__ void bar_wait(unsigned* slot, unsigned nblk){
  if (threadIdx.x == 0){
    while (__hip_atomic_load(slot, __ATOMIC_ACQUIRE, __HIP_MEMORY_SCOPE_AGENT) < nblk) { }
  }
  __syncthreads();
}
__device__ __forceinline__ void bar_arrive(unsigned* slot){
  __threadfence();
  __syncthreads();
  if (threadIdx.x == 0)
    __hip_atomic_fetch_add(slot, 1u, __ATOMIC_RELEASE, __HIP_MEMORY_SCOPE_AGENT);
}

// ---------------- setup kernels ----------------

__global__ void k_f32_to_f16(const float* __restrict__ s, f16* __restrict__ d, int n){
  int i = blockIdx.x*blockDim.x + threadIdx.x;
  if (i < n) d[i] = (f16)s[i];
}

__global__ void k_pad_w(const float* __restrict__ s, f16* __restrict__ d, int rows, int ks, int kd){
  int i = blockIdx.x*blockDim.x + threadIdx.x;
  if (i >= rows*kd) return;
  int r = i/kd, k = i - r*kd;
  d[i] = (k < ks) ? (f16)s[(size_t)r*ks + k] : (f16)0.f;
}

__global__ void k_bias(const float* __restrict__ a, const float* __restrict__ b,
                       float* __restrict__ d, int n){
  int i = blockIdx.x*blockDim.x + threadIdx.x;
  if (i < n) d[i] = a[i] + b[i];
}

__global__ void k_len(const float* __restrict__ x, int* __restrict__ len){
  int b = threadIdx.x;
  if (b < B_){
    int v = (int)x[((size_t)b*S_ + (S_-1))*E_];
    len[b] = v > S_ ? S_ : v;
  }
}

__global__ void k_init(f16* hf, f16* hr, f16* h1, unsigned* barA, unsigned* barC){
  int i = blockIdx.x*blockDim.x + threadIdx.x;
  if (i < 2*B_*H_){ hf[i] = (f16)1.f; hr[i] = (f16)1.f; h1[i] = (f16)1.f; }
  if (i < 2*S_) barA[i] = 0u;
  if (i < S_)   barC[i] = 0u;
}

// ---------------- phase A: persistent layer-0 fwd+rev ----------------
// grid (2,32,2) = 128 blocks, 256 thr, 64KB LDS -> >=2 blocks/CU capacity,
// grid <= 256 so all blocks co-resident with a plain launch.
// Block: 64 batch x 16 hidden x 4 gates. W_hh slice in LDS (64KB, staged once);
// W_ih slice streamed from L2. c,h-prev in regs; h dbuf in global; slot barrier
// per step per direction (the two directions never wait on each other).

__global__ __launch_bounds__(256, 1) void k_phaseA(
    const float* __restrict__ x,
    const f16* __restrict__ w0f, const f16* __restrict__ w0r,
    const f16* __restrict__ whf, const f16* __restrict__ whr,
    const float* __restrict__ bs0f, const float* __restrict__ bs0r,
    const int* __restrict__ len,
    f16* __restrict__ hbf, f16* __restrict__ hbr,
    f16* __restrict__ outcat, unsigned* __restrict__ bar)
{
  __shared__ f16 Wh[64*512];   // 64 KB exactly
  const int dir = blockIdx.z;
  const f16* wih = dir ? w0r : w0f;
  const f16* whh = dir ? whr : whf;
  const float* bias = dir ? bs0r : bs0f;
  f16* hb = dir ? hbr : hbf;
  unsigned* mybar = bar + dir*S_;
  const int tid = threadIdx.x;
  const int w = tid>>6, lane = tid&63, quad = lane>>4, l16 = lane&15;
  const int j0 = blockIdx.y*16;
  const int m0 = blockIdx.x*64 + w*16;

  // stage W_hh slice: 64 rows (4 gates x 16 hidden) x 512 k, xor-swizzled
  for (int u = tid; u < 4096; u += 256){
    int lrr = u>>6, uc = u&63;
    int g = lrr>>4, i = lrr&15;
    *(uint4*)&Wh[lrr*512 + (uc ^ (i&7))*8] =
        *(const uint4*)(whh + ((size_t)(g*H_ + j0 + i))*H_ + uc*8);
  }
  __syncthreads();

  const int j = j0 + l16;
  const int xsw = l16 & 7;
  // per-gate W_ih row pointers (streamed B operand, L2-resident)
  const f16* wiB0 = wih + (size_t)(0*H_ + j0 + l16)*EP_;
  const f16* wiB1 = wih + (size_t)(1*H_ + j0 + l16)*EP_;
  const f16* wiB2 = wih + (size_t)(2*H_ + j0 + l16)*EP_;
  const f16* wiB3 = wih + (size_t)(3*H_ + j0 + l16)*EP_;

  float bz[4], hprev[4], cpr[4]; int lm[4];
#pragma unroll
  for (int g = 0; g < 4; ++g) bz[g] = bias[g*H_ + j];
#pragma unroll
  for (int r = 0; r < 4; ++r){ hprev[r] = 1.f; cpr[r] = 1.f; lm[r] = len[m0 + quad*4 + r]; }

  int parity = 0;
  for (int s = 0; s < S_; ++s){
    const int t = dir ? (S_-1-s) : s;
    f32x4 z4 = {0.f,0.f,0.f,0.f};
    f32x4 acc[4] = {z4,z4,z4,z4};

    // --- x_t @ Wih^T (h-independent: issued BEFORE the barrier wait) ---
    const float* xr = x + ((size_t)(m0 + l16)*S_ + t)*E_;
#pragma unroll
    for (int kb = 0; kb < 9; ++kb){
      float4 f0 = *(const float4*)(xr + kb*32 + quad*8);
      float4 f1 = *(const float4*)(xr + kb*32 + quad*8 + 4);
      f16x8 a;
      a[0]=(f16)f0.x; a[1]=(f16)f0.y; a[2]=(f16)f0.z; a[3]=(f16)f0.w;
      a[4]=(f16)f1.x; a[5]=(f16)f1.y; a[6]=(f16)f1.z; a[7]=(f16)f1.w;
      acc[0] = __builtin_amdgcn_mfma_f32_16x16x32_f16(a, *(const f16x8*)(wiB0 + kb*32 + quad*8), acc[0],0,0,0);
      acc[1] = __builtin_amdgcn_mfma_f32_16x16x32_f16(a, *(const f16x8*)(wiB1 + kb*32 + quad*8), acc[1],0,0,0);
      acc[2] = __builtin_amdgcn_mfma_f32_16x16x32_f16(a, *(const f16x8*)(wiB2 + kb*32 + quad*8), acc[2],0,0,0);
      acc[3] = __builtin_amdgcn_mfma_f32_16x16x32_f16(a, *(const f16x8*)(wiB3 + kb*32 + quad*8), acc[3],0,0,0);
    }
    { // K tail 288..319 (x valid to 299; w0 pad rows are zero for k>=300)
      int kbase = 288 + quad*8;
      f16x8 a;
#pragma unroll
      for (int e2 = 0; e2 < 8; ++e2)
        a[e2] = (kbase + e2 < E_) ? (f16)xr[kbase + e2] : (f16)0.f;
      acc[0] = __builtin_amdgcn_mfma_f32_16x16x32_f16(a, *(const f16x8*)(wiB0 + 288 + quad*8), acc[0],0,0,0);
      acc[1] = __builtin_amdgcn_mfma_f32_16x16x32_f16(a, *(const f16x8*)(wiB1 + 288 + quad*8), acc[1],0,0,0);
      acc[2] = __builtin_amdgcn_mfma_f32_16x16x32_f16(a, *(const f16x8*)(wiB2 + 288 + quad*8), acc[2],0,0,0);
      acc[3] = __builtin_amdgcn_mfma_f32_16x16x32_f16(a, *(const f16x8*)(wiB3 + 288 + quad*8), acc[3],0,0,0);
    }

    // --- wait for step s-1 (all h writes of this direction) ---
    if (s > 0) bar_wait(mybar + s - 1, 64u);

    // --- h @ Whh^T (K=512), B from LDS ---
    const f16* hrow = hb + parity*(B_*H_) + (size_t)(m0 + l16)*H_ + quad*8;
#pragma unroll
    for (int kb = 0; kb < 16; ++kb){
      f16x8 a = *(const f16x8*)(hrow + kb*32);
      int uq = kb*4 + quad;
#pragma unroll
      for (int g = 0; g < 4; ++g){
        f16x8 b = *(const f16x8*)&Wh[(g*16+l16)*512 + (uq ^ xsw)*8];
        acc[g] = __builtin_amdgcn_mfma_f32_16x16x32_f16(a,b,acc[g],0,0,0);
      }
    }

    // --- gates + state update (c,h in regs; masked) ---
    f16* ho = hb + (1-parity)*(B_*H_);
#pragma unroll
    for (int r = 0; r < 4; ++r){
      int m = m0 + quad*4 + r;
      float zi = acc[0][r] + bz[0];
      float zf = acc[1][r] + bz[1];
      float zg = acc[2][r] + bz[2];
      float zo = acc[3][r] + bz[3];
      float ig = sigf(zi), fg = sigf(zf), gge = tanhf_(zg), og = sigf(zo);
      float cnew = fg*cpr[r] + ig*gge;
      float hnew = og*tanhf_(cnew);
      bool mk = t < lm[r];
      float hsel = mk ? hnew : hprev[r];
      float csel = mk ? cnew : cpr[r];
      hprev[r] = hsel; cpr[r] = csel;
      ho[(size_t)m*H_ + j] = (f16)hsel;
      outcat[((size_t)t*B_ + m)*D1_ + dir*H_ + j] = (f16)hsel;
    }
    bar_arrive(mybar + s);
    parity ^= 1;
  }
}

// ---------------- phase C: persistent layer-1 reverse ----------------
// grid (2,32,1) = 64 blocks. LDS: K-half [0,512) of W1_ih slice (64KB);
// K-half [512,1024) of W1_ih and all of W_hh1 streamed from L2.

__global__ __launch_bounds__(256, 1) void k_phaseC(
    const f16* __restrict__ outcat, const f16* __restrict__ w1i,
    const f16* __restrict__ w1h, const float* __restrict__ bs1r,
    const int* __restrict__ len,
    f16* __restrict__ h1b, float* __restrict__ h1f, unsigned* __restrict__ bar)
{
  __shared__ f16 Wl[64*512];   // 64 KB
  const int tid = threadIdx.x;
  const int w = tid>>6, lane = tid&63, quad = lane>>4, l16 = lane&15;
  const int j0 = blockIdx.y*16;
  const int m0 = blockIdx.x*64 + w*16;

  for (int u = tid; u < 4096; u += 256){
    int lrr = u>>6, uc = u&63;
    int g = lrr>>4, i = lrr&15;
    *(uint4*)&Wl[lrr*512 + (uc ^ (i&7))*8] =
        *(const uint4*)(w1i + ((size_t)(g*H_ + j0 + i))*D1_ + uc*8);
  }
  __syncthreads();

  const int j = j0 + l16;
  const int xsw = l16 & 7;
  const f16* wiB0 = w1i + (size_t)(0*H_ + j0 + l16)*D1_;
  const f16* wiB1 = w1i + (size_t)(1*H_ + j0 + l16)*D1_;
  const f16* wiB2 = w1i + (size_t)(2*H_ + j0 + l16)*D1_;
  const f16* wiB3 = w1i + (size_t)(3*H_ + j0 + l16)*D1_;
  const f16* whB0 = w1h + (size_t)(0*H_ + j0 + l16)*H_;
  const f16* whB1 = w1h + (size_t)(1*H_ + j0 + l16)*H_;
  const f16* whB2 = w1h + (size_t)(2*H_ + j0 + l16)*H_;
  const f16* whB3 = w1h + (size_t)(3*H_ + j0 + l16)*H_;

  float bz[4], hprev[4], cpr[4]; int lm[4];
#pragma unroll
  for (int g = 0; g < 4; ++g) bz[g] = bs1r[g*H_ + j];
#pragma unroll
  for (int r = 0; r < 4; ++r){ hprev[r] = 1.f; cpr[r] = 1.f; lm[r] = len[m0 + quad*4 + r]; }

  int parity = 0;
  for (int s = 0; s < S_; ++s){
    const int t = S_-1-s;
    f32x4 z4 = {0.f,0.f,0.f,0.f};
    f32x4 acc[4] = {z4,z4,z4,z4};

    // --- outcat_t @ W1ih^T (h-independent; before barrier wait) ---
    const f16* arow = outcat + ((size_t)t*B_ + m0 + l16)*D1_ + quad*8;
#pragma unroll
    for (int kb = 0; kb < 16; ++kb){    // K half from LDS
      f16x8 a = *(const f16x8*)(arow + kb*32);
      int uq = kb*4 + quad;
#pragma unroll
      for (int g = 0; g < 4; ++g){
        f16x8 b = *(const f16x8*)&Wl[(g*16+l16)*512 + (uq ^ xsw)*8];
        acc[g] = __builtin_amdgcn_mfma_f32_16x16x32_f16(a,b,acc[g],0,0,0);
      }
    }
#pragma unroll
    for (int kb = 16; kb < 32; ++kb){   // K half streamed from L2
      f16x8 a = *(const f16x8*)(arow + kb*32);
      acc[0] = __builtin_amdgcn_mfma_f32_16x16x32_f16(a, *(const f16x8*)(wiB0 + kb*32 + quad*8), acc[0],0,0,0);
      acc[1] = __builtin_amdgcn_mfma_f32_16x16x32_f16(a, *(const f16x8*)(wiB1 + kb*32 + quad*8), acc[1],0,0,0);
      acc[2] = __builtin_amdgcn_mfma_f32_16x16x32_f16(a, *(const f16x8*)(wiB2 + kb*32 + quad*8), acc[2],0,0,0);
      acc[3] = __builtin_amdgcn_mfma_f32_16x16x32_f16(a, *(const f16x8*)(wiB3 + kb*32 + quad*8), acc[3],0,0,0);
    }

    if (s > 0) bar_wait(bar + s - 1, 64u);

    // --- h @ Whh1^T (K=512), B streamed from L2 ---
    const f16* hrow = h1b + parity*(B_*H_) + (size_t)(m0 + l16)*H_ + quad*8;
#pragma unroll
    for (int kb = 0; kb < 16; ++kb){
      f16x8 a = *(const f16x8*)(hrow + kb*32);
      acc[0] = __builtin_amdgcn_mfma_f32_16x16x32_f16(a, *(const f16x8*)(whB0 + kb*32 + quad*8), acc[0],0,0,0);
      acc[1] = __builtin_amdgcn_mfma_f32_16x16x32_f16(a, *(const f16x8*)(whB1 + kb*32 + quad*8), acc[1],0,0,0);
      acc[2] = __builtin_amdgcn_mfma_f32_16x16x32_f16(a, *(const f16x8*)(whB2 + kb*32 + quad*8), acc[2],0,0,0);
      acc[3] = __builtin_amdgcn_mfma_f32_16x16x32_f16(a, *(const f16x8*)(whB3 + kb*32 + quad*8), acc[3],0,0,0);
    }

    f16* ho = h1b + (1-parity)*(B_*H_);
#pragma unroll
    for (int r = 0; r < 4; ++r){
      int m = m0 + quad*4 + r;
      float zi = acc[0][r] + bz[0];
      float zf = acc[1][r] + bz[1];
      float zg = acc[2][r] + bz[2];
      float zo = acc[3][r] + bz[3];
      float ig = sigf(zi), fg = sigf(zf), gge = tanhf_(zg), og = sigf(zo);
      float cnew = fg*cpr[r] + ig*gge;
      float hnew = og*tanhf_(cnew);
      bool mk = t < lm[r];
      float hsel = mk ? hnew : hprev[r];
      float csel = mk ? cnew : cpr[r];
      hprev[r] = hsel; cpr[r] = csel;
      ho[(size_t)m*H_ + j] = (f16)hsel;
      if (s == S_-1) h1f[(size_t)m*H_ + j] = hsel;
    }
    bar_arrive(bar + s);
    parity ^= 1;
  }
}

// ---------------- epilogue: folded FC ----------------

__global__ void k_fold(const float* __restrict__ fc1w, const float* __restrict__ fc1b,
                       const float* __restrict__ fcw,  const float* __restrict__ fcb,
                       float* __restrict__ Mf, float* __restrict__ bf){
  int i = blockIdx.x*blockDim.x + threadIdx.x;
  if (i >= 1024) return;
  int o = i >> 9, h = i & 511;
  float s = 0.f;
  for (int jj = 0; jj < 512; ++jj) s += fcw[o*512 + jj] * fc1w[jj*512 + h];
  Mf[o*512 + h] = s;
  if (h == 0){
    float sb = fcb[o];
    for (int jj = 0; jj < 512; ++jj) sb += fcw[o*512 + jj] * fc1b[jj];
    bf[o] = sb;
  }
}

__global__ void k_final(const float* __restrict__ h1f, const float* __restrict__ Mf,
                        const float* __restrict__ bf, float* __restrict__ out){
  int i = threadIdx.x;
  if (i >= 256) return;
  int b = i >> 1, o = i & 1;
  float s = bf[o];
  const float* hp = h1f + (size_t)b*512;
  const float* mp = Mf + (size_t)o*512;
  for (int h = 0; h < 512; ++h) s += hp[h]*mp[h];
  out[b*2 + o] = s;
}

// ---------------- host ----------------

extern "C" void kernel_launch(void* const* d_in, const int* in_sizes, int n_in,
                              void* d_out, int out_size, void* d_ws, size_t ws_size,
                              hipStream_t stream)
{
  const float* x     = (const float*)d_in[0];
  const float* wih0f = (const float*)d_in[1];
  const float* whh0f = (const float*)d_in[2];
  const float* bih0f = (const float*)d_in[3];
  const float* bhh0f = (const float*)d_in[4];
  const float* wih0r = (const float*)d_in[5];
  const float* whh0r = (const float*)d_in[6];
  const float* bih0r = (const float*)d_in[7];
  const float* bhh0r = (const float*)d_in[8];
  // d_in[9..12] = layer1 forward: dead code (only hT_r of layer1 reaches output)
  const float* wih1r = (const float*)d_in[13];
  const float* whh1r = (const float*)d_in[14];
  const float* bih1r = (const float*)d_in[15];
  const float* bhh1r = (const float*)d_in[16];
  const float* fc1w  = (const float*)d_in[17];
  const float* fc1b  = (const float*)d_in[18];
  const float* fcw   = (const float*)d_in[19];
  const float* fcb   = (const float*)d_in[20];
  float* out = (float*)d_out;

  char* p = (char*)d_ws;
  auto alloc = [&](size_t bytes)->char*{
    char* r = p; p += (bytes + 255) & ~(size_t)255; return r;
  };
  f16* w0fp   = (f16*)alloc((size_t)G_*EP_*2);
  f16* w0rp   = (f16*)alloc((size_t)G_*EP_*2);
  f16* whf    = (f16*)alloc((size_t)G_*H_*2);
  f16* whr    = (f16*)alloc((size_t)G_*H_*2);
  f16* w1h    = (f16*)alloc((size_t)G_*H_*2);
  f16* w1i    = (f16*)alloc((size_t)G_*D1_*2);
  float* bs0f = (float*)alloc(G_*4);
  float* bs0r = (float*)alloc(G_*4);
  float* bs1r = (float*)alloc(G_*4);
  int*   len  = (int*)alloc(B_*4);
  f16* outcat = (f16*)alloc((size_t)S_*B_*D1_*2);   // 67 MB
  f16* hf     = (f16*)alloc((size_t)2*B_*H_*2);
  f16* hr     = (f16*)alloc((size_t)2*B_*H_*2);
  f16* h1     = (f16*)alloc((size_t)2*B_*H_*2);
  float* h1f  = (float*)alloc((size_t)B_*H_*4);
  float* Mf   = (float*)alloc(2*512*4);
  float* bf   = (float*)alloc(256);
  unsigned* barA = (unsigned*)alloc(2*S_*4);
  unsigned* barC = (unsigned*)alloc(S_*4);
  // total ~81 MB

  int n;
  n = G_*EP_;    k_pad_w<<<(n+255)/256, 256, 0, stream>>>(wih0f, w0fp, G_, E_, EP_);
                 k_pad_w<<<(n+255)/256, 256, 0, stream>>>(wih0r, w0rp, G_, E_, EP_);
  n = G_*H_;     k_f32_to_f16<<<(n+255)/256,256,0,stream>>>(whh0f, whf, n);
                 k_f32_to_f16<<<(n+255)/256,256,0,stream>>>(whh0r, whr, n);
                 k_f32_to_f16<<<(n+255)/256,256,0,stream>>>(whh1r, w1h, n);
  n = G_*D1_;    k_f32_to_f16<<<(n+255)/256,256,0,stream>>>(wih1r, w1i, n);
  k_bias<<<8,256,0,stream>>>(bih0f, bhh0f, bs0f, G_);
  k_bias<<<8,256,0,stream>>>(bih0r, bhh0r, bs0r, G_);
  k_bias<<<8,256,0,stream>>>(bih1r, bhh1r, bs1r, G_);
  k_len<<<1,128,0,stream>>>(x, len);
  n = 2*B_*H_; k_init<<<(n+255)/256,256,0,stream>>>(hf, hr, h1, barA, barC);
  k_fold<<<4,256,0,stream>>>(fc1w, fc1b, fcw, fcb, Mf, bf);

  k_phaseA<<<dim3(2,32,2), 256, 0, stream>>>(
      x, w0fp, w0rp, whf, whr, bs0f, bs0r, len, hf, hr, outcat, barA);

  k_phaseC<<<dim3(2,32,1), 256, 0, stream>>>(
      outcat, w1i, w1h, bs1r, len, h1, h1f, barC);

  k_final<<<1,256,0,stream>>>(h1f, Mf, bf, out);
}